// Round 2
// baseline (766.364 us; speedup 1.0000x reference)
//
#include <hip/hip_runtime.h>
#include <math.h>

#define NO_LAYERS 2048
#define MODES 4096
#define APL 8
#define OUT_N (NO_LAYERS * APL)   // 16384
#define NBLK 1024                 // must equal gridDim.x; 4 blocks/CU * 256 CUs

// Native clang vector type — required by __builtin_nontemporal_load
// (HIP's float4 class is rejected by the builtin's type check).
typedef float nf4 __attribute__((ext_vector_type(4)));

// Re(tanh(t*(Sr+i*Si))), numerically stable for |t*Sr| up to thousands.
// Re tanh(x+iy) = sinh(2x)/(cosh(2x)+cos(2y))
//              = sign(x)*(1-e^{-2a}) / (1+e^{-2a}+2 e^{-a} cos(2y)),  a=2|x|
__device__ __forceinline__ float retanh_cplx(float t, float Sr, float Si) {
    float x = t * Sr;
    float y = t * Si;
    float a = 2.0f * fabsf(x);
    float e1 = expf(-a);          // 0 for a > ~88 (saturated regime)
    float e2 = e1 * e1;
    float num = 1.0f - e2;
    float den = 1.0f + e2 + 2.0f * e1 * cosf(2.0f * y);
    return copysignf(num / den, x);
}

// R2: single persistent kernel. 1024 blocks x 256 threads, co-resident by
// construction (__launch_bounds__(256,4) caps VGPR at 128 -> 4 blocks/CU;
// LDS 16.2 KB < 40 KB/block budget; grid == 4*256 CUs). Phase 1 computes
// S/t + 4 lin1 rows per block; a device-scope atomic gate replaces the old
// kernel boundary so the 268 MB lin2 stream (register-prefetched before the
// gate) overlaps phase 1 instead of serializing behind it.
__global__ void __launch_bounds__(256, 4)
k_fused(const float* __restrict__ model_p,
        const float* __restrict__ wf0,
        const float* __restrict__ wf1,
        const float* __restrict__ wf2,
        const float* __restrict__ l1w,
        const float* __restrict__ l1b,
        const float* __restrict__ l2w,
        const float* __restrict__ l2b,
        float* __restrict__ h,
        unsigned int* __restrict__ flag,
        float* __restrict__ out) {
    __shared__ float buf[MODES];   // 16 KB; ts = buf[0:2048] in ph1, hs = buf[0:4096] in ph2
    __shared__ float red[3][2][4];
    __shared__ float S[3][2];
    const int tid = threadIdx.x;            // 0..255
    const int wave = tid >> 6, lane = tid & 63;

    // ---- issue phase-1 weight stream immediately (no deps): 1 lin1 row/wave ----
    const int r1 = blockIdx.x * 4 + wave;   // < 4096
    const nf4* wp = (const nf4*)(l1w + (size_t)r1 * NO_LAYERS);
    nf4 wv[8];                               // 32 VGPRs
    #pragma unroll
    for (int i = 0; i < 8; i++) wv[i] = __builtin_nontemporal_load(&wp[i * 64 + lane]);

    // ---- S0..S2: complex sums of w_fft (L2-hot after first blocks) ----
    const float* wptr[3] = {wf0, wf1, wf2};
    float sr[3] = {0.f, 0.f, 0.f}, si[3] = {0.f, 0.f, 0.f};
    #pragma unroll
    for (int q = 0; q < 3; q++) {
        const float2* p = (const float2*)wptr[q];   // interleaved re,im
        #pragma unroll
        for (int i = 0; i < MODES / 256; i++) {     // 16 iters
            float2 v = p[i * 256 + tid];
            sr[q] += v.x; si[q] += v.y;
        }
    }
    #pragma unroll
    for (int off = 32; off > 0; off >>= 1) {
        #pragma unroll
        for (int q = 0; q < 3; q++) {
            sr[q] += __shfl_down(sr[q], off);
            si[q] += __shfl_down(si[q], off);
        }
    }
    if (lane == 0) {
        #pragma unroll
        for (int q = 0; q < 3; q++) { red[q][0][wave] = sr[q]; red[q][1][wave] = si[q]; }
    }
    __syncthreads();
    if (tid < 6) {
        int q = tid >> 1, c = tid & 1;
        S[q][c] = red[q][c][0] + red[q][c][1] + red[q][c][2] + red[q][c][3];
    }
    __syncthreads();
    const float S0r = S[0][0], S0i = S[0][1];
    const float S1r = S[1][0], S1i = S[1][1];
    const float S2r = S[2][0], S2i = S[2][1];

    // ---- t[2048] into LDS: strided model_p column (L2-hot) + 3 complex tanh ----
    #pragma unroll
    for (int k = 0; k < NO_LAYERS / 256; k++) {      // 8 iters
        const int f = k * 256 + tid;
        float t = model_p[(size_t)f * MODES];        // column 0 of model_p
        t = retanh_cplx(t, S0r, S0i);
        t = retanh_cplx(t, S1r, S1i);
        t = retanh_cplx(t, S2r, S2i);
        buf[f] = t;
    }
    __syncthreads();

    // ---- lin1 row dot from LDS; weights already in registers ----
    {
        const float4* tp = (const float4*)buf;
        float acc = 0.f;
        #pragma unroll
        for (int i = 0; i < 8; i++) {
            float4 tv = tp[i * 64 + lane];
            acc += wv[i].x * tv.x + wv[i].y * tv.y + wv[i].z * tv.z + wv[i].w * tv.w;
        }
        #pragma unroll
        for (int off = 32; off > 0; off >>= 1) acc += __shfl_down(acc, off);
        if (lane == 0) h[r1] = tanhf(acc + l1b[r1]);
    }

    // ---- prefetch head of the lin2 stream BEFORE the gate (no dep on h):
    //      4 rows/wave, first 2 of 16 iterations (32 VGPRs) ----
    const int r2 = blockIdx.x * 16 + wave * 4;       // < 16384
    const nf4* qv = (const nf4*)(l2w + (size_t)r2 * MODES);   // row stride 1024 nf4
    nf4 pw[2][4];
    #pragma unroll
    for (int j = 0; j < 2; j++) {
        const int idx = j * 64 + lane;
        #pragma unroll
        for (int r = 0; r < 4; r++)
            pw[j][r] = __builtin_nontemporal_load(&qv[r * (MODES / 4) + idx]);
    }

    // ---- device-scope gate: publish h, wait for all 1024 blocks ----
    __threadfence();              // release each thread's h store (agent scope)
    __syncthreads();              // all waves of this block arrived
    if (tid == 0) {
        __hip_atomic_fetch_add(flag, 1u, __ATOMIC_RELEASE, __HIP_MEMORY_SCOPE_AGENT);
        while (__hip_atomic_load(flag, __ATOMIC_ACQUIRE, __HIP_MEMORY_SCOPE_AGENT) < NBLK)
            __builtin_amdgcn_s_sleep(2);
    }
    __syncthreads();
    __threadfence();              // acquire: invalidate stale cached h

    // ---- stage h (16 KB) into LDS (reuses buf; t is dead) ----
    {
        const float4* hp = (const float4*)h;
        float4* sp = (float4*)buf;
        #pragma unroll
        for (int i = 0; i < (MODES / 4) / 256; i++) sp[i * 256 + tid] = hp[i * 256 + tid];
    }
    __syncthreads();

    // ---- lin2: 4 rows/wave, NT streamed ----
    const float4* hb = (const float4*)buf;
    float a0 = 0.f, a1 = 0.f, a2 = 0.f, a3 = 0.f;
    #pragma unroll
    for (int j = 0; j < 2; j++) {                    // prefetched head
        float4 hv = hb[j * 64 + lane];
        a0 += pw[j][0].x * hv.x + pw[j][0].y * hv.y + pw[j][0].z * hv.z + pw[j][0].w * hv.w;
        a1 += pw[j][1].x * hv.x + pw[j][1].y * hv.y + pw[j][1].z * hv.z + pw[j][1].w * hv.w;
        a2 += pw[j][2].x * hv.x + pw[j][2].y * hv.y + pw[j][2].z * hv.z + pw[j][2].w * hv.w;
        a3 += pw[j][3].x * hv.x + pw[j][3].y * hv.y + pw[j][3].z * hv.z + pw[j][3].w * hv.w;
    }
    #pragma unroll 2
    for (int i = 2; i < 16; i++) {                   // 14 streamed iters
        const int idx = i * 64 + lane;
        float4 hv = hb[idx];
        nf4 v0 = __builtin_nontemporal_load(&qv[0 * (MODES / 4) + idx]);
        nf4 v1 = __builtin_nontemporal_load(&qv[1 * (MODES / 4) + idx]);
        nf4 v2 = __builtin_nontemporal_load(&qv[2 * (MODES / 4) + idx]);
        nf4 v3 = __builtin_nontemporal_load(&qv[3 * (MODES / 4) + idx]);
        a0 += v0.x * hv.x + v0.y * hv.y + v0.z * hv.z + v0.w * hv.w;
        a1 += v1.x * hv.x + v1.y * hv.y + v1.z * hv.z + v1.w * hv.w;
        a2 += v2.x * hv.x + v2.y * hv.y + v2.z * hv.z + v2.w * hv.w;
        a3 += v3.x * hv.x + v3.y * hv.y + v3.z * hv.z + v3.w * hv.w;
    }
    #pragma unroll
    for (int off = 32; off > 0; off >>= 1) {
        a0 += __shfl_down(a0, off);
        a1 += __shfl_down(a1, off);
        a2 += __shfl_down(a2, off);
        a3 += __shfl_down(a3, off);
    }
    if (lane == 0) {
        out[r2]     = a0 + l2b[r2];
        out[r2 + 1] = a1 + l2b[r2 + 1];
        out[r2 + 2] = a2 + l2b[r2 + 2];
        out[r2 + 3] = a3 + l2b[r2 + 3];
    }
}

extern "C" void kernel_launch(void* const* d_in, const int* in_sizes, int n_in,
                              void* d_out, int out_size, void* d_ws, size_t ws_size,
                              hipStream_t stream) {
    const float* model_p = (const float*)d_in[0];
    const float* wf0     = (const float*)d_in[1];   // complex64 interleaved
    const float* wf1     = (const float*)d_in[2];
    const float* wf2     = (const float*)d_in[3];
    const float* lin1_w  = (const float*)d_in[4];
    const float* lin1_b  = (const float*)d_in[5];
    const float* lin2_w  = (const float*)d_in[6];
    const float* lin2_b  = (const float*)d_in[7];
    float* out = (float*)d_out;

    float* h = (float*)d_ws;                                    // 4096 floats
    unsigned int* flag = (unsigned int*)((char*)d_ws + MODES * sizeof(float));

    // zero the arrival counter (workspace is re-poisoned each iteration);
    // async memset is graph-capturable (no alloc/free/sync/event here).
    hipMemsetAsync(flag, 0, sizeof(unsigned int), stream);
    k_fused<<<NBLK, 256, 0, stream>>>(model_p, wf0, wf1, wf2,
                                      lin1_w, lin1_b, lin2_w, lin2_b,
                                      h, flag, out);
}

// Round 3
// 388.556 us; speedup vs baseline: 1.9723x; 1.9723x over previous
//
#include <hip/hip_runtime.h>
#include <math.h>

#define NO_LAYERS 2048
#define MODES 4096
#define APL 8
#define OUT_N (NO_LAYERS * APL)   // 16384

// Native clang vector type — required by __builtin_nontemporal_load
// (HIP's float4 class is rejected by the builtin's type check).
typedef float nf4 __attribute__((ext_vector_type(4)));

// Re(tanh(t*(Sr+i*Si))), numerically stable for |t*Sr| up to thousands.
// Re tanh(x+iy) = sinh(2x)/(cosh(2x)+cos(2y))
//              = sign(x)*(1-e^{-2a}) / (1+e^{-2a}+2 e^{-a} cos(2y)),  a=2|x|
__device__ __forceinline__ float retanh_cplx(float t, float Sr, float Si) {
    float x = t * Sr;
    float y = t * Si;
    float a = 2.0f * fabsf(x);
    float e1 = expf(-a);          // 0 for a > ~88 (saturated regime)
    float e2 = e1 * e1;
    float num = 1.0f - e2;
    float den = 1.0f + e2 + 2.0f * e1 * cosf(2.0f * y);
    return copysignf(num / den, x);
}

// R3: revert to the R1 two-kernel structure (387.4 us, best verified).
// R2's persistent-gate fusion regressed 8x: VGPR_Count=40 proved the
// compiler sank the register prefetches past the gate fences, and the
// gate itself added ~400 us of latency pathology at 335 GB/s. Do not
// re-attempt device-scope gates on this problem.
//
// FUSED prep + lin1: S0..S2 are sums over 96 KB of w_fft (L2-resident),
// t is 24 transcendental ops/thread of VALU work overlapping the NT
// weight stream; the 8 NT weight loads per lane are issued FIRST.
__global__ void __launch_bounds__(256) k_lin1f(const float* __restrict__ model_p,
                                               const float* __restrict__ w0,
                                               const float* __restrict__ w1,
                                               const float* __restrict__ w2,
                                               const float* __restrict__ w,
                                               const float* __restrict__ b,
                                               float* __restrict__ h) {
    __shared__ float red[3][2][4];
    __shared__ float S[3][2];
    __shared__ float ts[NO_LAYERS];          // 8 KB
    const int tid = threadIdx.x;             // 0..255
    const int wave = tid >> 6, lane = tid & 63;

    // ---- issue the read-once weight stream immediately (no deps) ----
    const int row = blockIdx.x * 4 + wave;   // < 4096
    const nf4* wp = (const nf4*)(w + (size_t)row * NO_LAYERS);
    nf4 wv[(NO_LAYERS / 4) / 64];            // 8 x 16B = 32 VGPRs
    #pragma unroll
    for (int i = 0; i < (NO_LAYERS / 4) / 64; i++)
        wv[i] = __builtin_nontemporal_load(&wp[i * 64 + lane]);

    // ---- S0..S2: complex sums of w_fft (cached loads: reused by all blocks) ----
    const float* wptr[3] = {w0, w1, w2};
    float sr[3] = {0.f, 0.f, 0.f}, si[3] = {0.f, 0.f, 0.f};
    #pragma unroll
    for (int q = 0; q < 3; q++) {
        const float2* p = (const float2*)wptr[q];   // interleaved re,im
        #pragma unroll
        for (int i = 0; i < MODES / 256; i++) {     // 16 iters
            float2 v = p[i * 256 + tid];
            sr[q] += v.x; si[q] += v.y;
        }
    }
    #pragma unroll
    for (int off = 32; off > 0; off >>= 1) {
        #pragma unroll
        for (int q = 0; q < 3; q++) {
            sr[q] += __shfl_down(sr[q], off);
            si[q] += __shfl_down(si[q], off);
        }
    }
    if (lane == 0) {
        #pragma unroll
        for (int q = 0; q < 3; q++) { red[q][0][wave] = sr[q]; red[q][1][wave] = si[q]; }
    }
    __syncthreads();
    if (tid < 6) {
        int q = tid >> 1, c = tid & 1;
        S[q][c] = red[q][c][0] + red[q][c][1] + red[q][c][2] + red[q][c][3];
    }
    __syncthreads();
    const float S0r = S[0][0], S0i = S[0][1];
    const float S1r = S[1][0], S1i = S[1][1];
    const float S2r = S[2][0], S2i = S[2][1];

    // ---- t[2048]: one strided model_p column read (L2-hot after block 0)
    //      + 3 chained complex tanh per element ----
    #pragma unroll
    for (int k = 0; k < NO_LAYERS / 256; k++) {      // 8 iters
        const int f = k * 256 + tid;
        float t = model_p[(size_t)f * MODES];        // column 0 of model_p
        t = retanh_cplx(t, S0r, S0i);
        t = retanh_cplx(t, S1r, S1i);
        t = retanh_cplx(t, S2r, S2i);
        ts[f] = t;
    }
    __syncthreads();

    // ---- lin1 row dot from LDS; weights already in registers ----
    const float4* tp = (const float4*)ts;
    float acc = 0.f;
    #pragma unroll
    for (int i = 0; i < (NO_LAYERS / 4) / 64; i++) {   // 8 iters
        float4 tv = tp[i * 64 + lane];
        acc += wv[i].x * tv.x + wv[i].y * tv.y + wv[i].z * tv.z + wv[i].w * tv.w;
    }
    #pragma unroll
    for (int off = 32; off > 0; off >>= 1) acc += __shfl_down(acc, off);
    if (lane == 0) h[row] = tanhf(acc + b[row]);
}

// out[j] = dot(h, lin2_w[j,:]) + b[j];  lin2_w: (16384, 4096) row-major.
// Two rows per wave, h staged in LDS, streaming weights non-temporal
// (read-once 268 MB stream). R3: first SIX weight iterations per row are
// prefetched into registers (12 x 16B = 48 VGPRs) BEFORE the h->LDS
// staging barrier, so 3/8 of the stream is in flight at block launch.
__global__ void __launch_bounds__(256) k_lin2(const float* __restrict__ h,
                                              const float* __restrict__ w,
                                              const float* __restrict__ b,
                                              float* __restrict__ out) {
    __shared__ float hs[MODES];              // 16 KB
    const int tid = threadIdx.x;
    const int wave = tid >> 6, lane = tid & 63;
    const int row0 = blockIdx.x * 8 + wave * 2;   // 2048 blocks * 8 rows = 16384
    const nf4* wp0 = (const nf4*)(w + (size_t)row0 * MODES);
    const nf4* wp1 = (const nf4*)(w + (size_t)(row0 + 1) * MODES);

    // prefetch first 6 iterations of both weight rows (12 x 16B = 48 VGPRs)
    nf4 pw0[6], pw1[6];
    #pragma unroll
    for (int i = 0; i < 6; i++) {
        pw0[i] = __builtin_nontemporal_load(&wp0[i * 64 + lane]);
        pw1[i] = __builtin_nontemporal_load(&wp1[i * 64 + lane]);
    }

    {   // stage h (16 KB) to LDS
        const float4* hp = (const float4*)h;
        float4* sp = (float4*)hs;
        #pragma unroll
        for (int i = 0; i < (MODES / 4) / 256; i++) sp[i * 256 + tid] = hp[i * 256 + tid];
    }
    __syncthreads();

    const float4* hp = (const float4*)hs;
    float acc0 = 0.f, acc1 = 0.f;
    #pragma unroll
    for (int i = 0; i < 6; i++) {                     // prefetched head
        float4 hv = hp[i * 64 + lane];
        acc0 += pw0[i].x * hv.x + pw0[i].y * hv.y + pw0[i].z * hv.z + pw0[i].w * hv.w;
        acc1 += pw1[i].x * hv.x + pw1[i].y * hv.y + pw1[i].z * hv.z + pw1[i].w * hv.w;
    }
    #pragma unroll
    for (int i = 6; i < (MODES / 4) / 64; i++) {      // 10 streamed iters
        const int idx = i * 64 + lane;
        float4 hv = hp[idx];
        nf4 w0v = __builtin_nontemporal_load(&wp0[idx]);
        nf4 w1v = __builtin_nontemporal_load(&wp1[idx]);
        acc0 += w0v.x * hv.x + w0v.y * hv.y + w0v.z * hv.z + w0v.w * hv.w;
        acc1 += w1v.x * hv.x + w1v.y * hv.y + w1v.z * hv.z + w1v.w * hv.w;
    }
    #pragma unroll
    for (int off = 32; off > 0; off >>= 1) {
        acc0 += __shfl_down(acc0, off);
        acc1 += __shfl_down(acc1, off);
    }
    if (lane == 0) {
        out[row0]     = acc0 + b[row0];
        out[row0 + 1] = acc1 + b[row0 + 1];
    }
}

extern "C" void kernel_launch(void* const* d_in, const int* in_sizes, int n_in,
                              void* d_out, int out_size, void* d_ws, size_t ws_size,
                              hipStream_t stream) {
    const float* model_p = (const float*)d_in[0];
    const float* w0      = (const float*)d_in[1];   // complex64 interleaved
    const float* w1      = (const float*)d_in[2];
    const float* w2      = (const float*)d_in[3];
    const float* lin1_w  = (const float*)d_in[4];
    const float* lin1_b  = (const float*)d_in[5];
    const float* lin2_w  = (const float*)d_in[6];
    const float* lin2_b  = (const float*)d_in[7];
    float* out = (float*)d_out;

    float* h = (float*)d_ws;          // 4096 floats

    k_lin1f<<<1024, 256, 0, stream>>>(model_p, w0, w1, w2, lin1_w, lin1_b, h);
    k_lin2<<<2048, 256, 0, stream>>>(h, lin2_w, lin2_b, out);
}